// Round 23
// baseline (212.897 us; speedup 1.0000x reference)
//
#include <hip/hip_runtime.h>

#define HIDDEN 128
#define NCHUNK 256
#define CBITS  9            // 512 nodes per coarse bucket (needs N < 2^17)

typedef float v2f __attribute__((ext_vector_type(2)));
typedef short short8 __attribute__((ext_vector_type(8)));
typedef float f32x4 __attribute__((ext_vector_type(4)));
__device__ __forceinline__ v2f v2s(float a) { v2f r; r.x = a; r.y = a; return r; }

// bf16 split helpers (RNE)
__device__ __forceinline__ ushort f2bf(float f) {
    uint u = __float_as_uint(f);
    u += 0x7FFFu + ((u >> 16) & 1u);
    return (ushort)(u >> 16);
}
__device__ __forceinline__ float bf2f(ushort h) {
    return __uint_as_float(((uint)h) << 16);
}

// ============== CSR build via two-level counting sort (NO global atomics) ===
__global__ __launch_bounds__(256)
void k_bhist(const int* __restrict__ dst, int* __restrict__ bh, int E, int CS) {
    __shared__ int h[256];
    int c = blockIdx.x;
    h[threadIdx.x] = 0;
    __syncthreads();
    int beg = c * CS, end = min(E, beg + CS);
    for (int e = beg + threadIdx.x; e < end; e += 256)
        atomicAdd(&h[dst[e] >> CBITS], 1);
    __syncthreads();
    bh[c * 256 + threadIdx.x] = h[threadIdx.x];
}

__global__ __launch_bounds__(256)
void k_cscan(const int* __restrict__ bh, int* __restrict__ choff,
             int* __restrict__ bbase) {
    __shared__ int sm[256];
    int b = threadIdx.x;
    int acc = 0;
    for (int c = 0; c < NCHUNK; c += 8) {
        int v[8];
#pragma unroll
        for (int i = 0; i < 8; ++i) v[i] = bh[(c + i) * 256 + b];
#pragma unroll
        for (int i = 0; i < 8; ++i) { choff[(c + i) * 256 + b] = acc; acc += v[i]; }
    }
    int tot = acc;
    sm[b] = tot;
    __syncthreads();
    int run = tot;
    for (int d = 1; d < 256; d <<= 1) {
        int t = (b >= d) ? sm[b - d] : 0;
        __syncthreads();
        run += t;
        sm[b] = run;
        __syncthreads();
    }
    bbase[b] = run - tot;              // exclusive
    if (b == 255) bbase[256] = run;    // == E
}

__global__ __launch_bounds__(256)
void k_scatter(const int* __restrict__ src, const int* __restrict__ dst,
               const float* __restrict__ ew, const int* __restrict__ choff,
               const int* __restrict__ bbase, int2* __restrict__ staged,
               int E, int CS) {
    __shared__ int cur[256];
    int c = blockIdx.x;
    cur[threadIdx.x] = bbase[threadIdx.x] + choff[c * 256 + threadIdx.x];
    __syncthreads();
    int beg = c * CS, end = min(E, beg + CS);
    for (int e = beg + threadIdx.x; e < end; e += 256) {
        int d = dst[e];
        int slot = atomicAdd(&cur[d >> CBITS], 1);
        int2 p;
        p.x = src[e] | ((d & 511) << 17);
        p.y = __float_as_int(ew[e]);
        staged[slot] = p;
    }
}

// Pass D: per-bucket fine CSR + FUSED layer-1 aggregation (R22).
// R23: cpack keeps (src | dl<<17) verbatim so downstream kernels can
// recover the bucket-local dst without bbase.
__global__ __launch_bounds__(512)
void k_fine(const int2* __restrict__ staged, const int* __restrict__ bbase,
            const float* __restrict__ x,
            int* __restrict__ offs, int2* __restrict__ cpack,
            float4* __restrict__ yv, int N) {
    __shared__ int fc[512];
    __shared__ int fo[512];
    __shared__ int sm[512];
    __shared__ float agg[1024];
    int b = blockIdx.x;
    int t = threadIdx.x;
    int ebeg = bbase[b], eend = bbase[b + 1];
    fc[t] = 0;
    agg[t] = 0.f;
    agg[t + 512] = 0.f;
    __syncthreads();
    for (int e = ebeg + t; e < eend; e += 512)
        atomicAdd(&fc[(staged[e].x >> 17) & 511], 1);
    __syncthreads();
    // exclusive scan of 512 (1 elem/thread)
    int v = fc[t];
    sm[t] = v;
    __syncthreads();
    int run = v;
    for (int d = 1; d < 512; d <<= 1) {
        int u = (t >= d) ? sm[t - d] : 0;
        __syncthreads();
        run += u;
        sm[t] = run;
        __syncthreads();
    }
    fo[t] = run - v;                   // exclusive
    __syncthreads();
    int nb0 = b << CBITS;
    int node = nb0 + t;
    if (node < N) offs[node] = ebeg + fo[t];
    __syncthreads();                   // offs reads of fo done before cursor use
    for (int e = ebeg + t; e < eend; e += 512) {
        int2 p = staged[e];
        int dl = (p.x >> 17) & 511;
        int srcn = p.x & 0x1FFFF;
        float w = __int_as_float(p.y);
        int ls = atomicAdd(&fo[dl], 1);
        cpack[ebeg + ls] = p;          // keep dl bits for gather3
        float2 xv = *reinterpret_cast<const float2*>(x + (size_t)srcn * 2);
        atomicAdd(&agg[dl * 2 + 0], w * xv.x);
        atomicAdd(&agg[dl * 2 + 1], w * xv.y);
    }
    __syncthreads();
    if (node < N) {
        float2 xi = *reinterpret_cast<const float2*>(x + (size_t)node * 2);
        yv[node] = make_float4(agg[2 * t], agg[2 * t + 1], xi.x, xi.y);
    }
}

__device__ __forceinline__ int end_of(const int* offs, int i, int N, int E) {
    return (i + 1 < N) ? offs[i + 1] : E;
}

// ================= fused layer-2 aggregation (+ implicit layer-1) ===========
// (R20 structure; R23: readlane result masked with 0x1FFFF — cpack.x now
// carries dl in bits 17+; the AND stays on the scalar path.)
#define EDGE4(sK, wK)                                              \
    {                                                              \
        v2f t = B + v2s((sK).x) * WR0 + v2s((sK).y) * WR1          \
                  + v2s((sK).z) * WO0 + v2s((sK).w) * WO1;         \
        t = __builtin_elementwise_max(t, Z);                       \
        acc = acc + v2s(wK) * t;                                   \
    }

__global__ __launch_bounds__(256)
void k_gatherfused(const int* __restrict__ offs, const int2* __restrict__ cpack,
                   const float4* __restrict__ yv,
                   const float* __restrict__ W1rel, const float* __restrict__ b1,
                   const float* __restrict__ W1root,
                   ushort* __restrict__ a_hi, ushort* __restrict__ a_lo,
                   int N, int E) {
    int wv   = (blockIdx.x * 256 + threadIdx.x) >> 6;
    int lane = threadIdx.x & 63;
    if (wv >= N) return;
    wv = __builtin_amdgcn_readfirstlane(wv);   // force scalar: loop control uniform

    const int c0 = lane * 2;
    const v2f WR0 = *reinterpret_cast<const v2f*>(W1rel  + c0);
    const v2f WR1 = *reinterpret_cast<const v2f*>(W1rel  + HIDDEN + c0);
    const v2f WO0 = *reinterpret_cast<const v2f*>(W1root + c0);
    const v2f WO1 = *reinterpret_cast<const v2f*>(W1root + HIDDEN + c0);
    const v2f B   = *reinterpret_cast<const v2f*>(b1 + c0);
    const v2f Z   = {0.f, 0.f};

    int start = offs[wv];
    int end   = (wv + 1 < N) ? offs[wv + 1] : E;
    v2f acc = {0.f, 0.f};

    for (int base = start; base < end; base += 64) {
        int nb = min(64, end - base);
        int sx = 0, wb = 0;
        if (lane < nb) {                       // ONE coalesced 8B/lane load
            int2 p = cpack[base + lane];
            sx = p.x; wb = p.y;
        }
        int k = 0;
        for (; k + 8 <= nb; k += 8) {
            int s0 = __builtin_amdgcn_readlane(sx, k + 0) & 0x1FFFF;
            int s1 = __builtin_amdgcn_readlane(sx, k + 1) & 0x1FFFF;
            int s2 = __builtin_amdgcn_readlane(sx, k + 2) & 0x1FFFF;
            int s3 = __builtin_amdgcn_readlane(sx, k + 3) & 0x1FFFF;
            int s4 = __builtin_amdgcn_readlane(sx, k + 4) & 0x1FFFF;
            int s5 = __builtin_amdgcn_readlane(sx, k + 5) & 0x1FFFF;
            int s6 = __builtin_amdgcn_readlane(sx, k + 6) & 0x1FFFF;
            int s7 = __builtin_amdgcn_readlane(sx, k + 7) & 0x1FFFF;
            float4 y0 = yv[s0]; float4 y1 = yv[s1];
            float4 y2 = yv[s2]; float4 y3 = yv[s3];
            float4 y4 = yv[s4]; float4 y5 = yv[s5];
            float4 y6 = yv[s6]; float4 y7 = yv[s7];
            float w0 = __int_as_float(__builtin_amdgcn_readlane(wb, k + 0));
            float w1 = __int_as_float(__builtin_amdgcn_readlane(wb, k + 1));
            float w2 = __int_as_float(__builtin_amdgcn_readlane(wb, k + 2));
            float w3 = __int_as_float(__builtin_amdgcn_readlane(wb, k + 3));
            float w4 = __int_as_float(__builtin_amdgcn_readlane(wb, k + 4));
            float w5 = __int_as_float(__builtin_amdgcn_readlane(wb, k + 5));
            float w6 = __int_as_float(__builtin_amdgcn_readlane(wb, k + 6));
            float w7 = __int_as_float(__builtin_amdgcn_readlane(wb, k + 7));
            EDGE4(y0, w0) EDGE4(y1, w1) EDGE4(y2, w2) EDGE4(y3, w3)
            EDGE4(y4, w4) EDGE4(y5, w5) EDGE4(y6, w6) EDGE4(y7, w7)
        }
        for (; k + 4 <= nb; k += 4) {
            int s0 = __builtin_amdgcn_readlane(sx, k + 0) & 0x1FFFF;
            int s1 = __builtin_amdgcn_readlane(sx, k + 1) & 0x1FFFF;
            int s2 = __builtin_amdgcn_readlane(sx, k + 2) & 0x1FFFF;
            int s3 = __builtin_amdgcn_readlane(sx, k + 3) & 0x1FFFF;
            float4 y0 = yv[s0]; float4 y1 = yv[s1];
            float4 y2 = yv[s2]; float4 y3 = yv[s3];
            float w0 = __int_as_float(__builtin_amdgcn_readlane(wb, k + 0));
            float w1 = __int_as_float(__builtin_amdgcn_readlane(wb, k + 1));
            float w2 = __int_as_float(__builtin_amdgcn_readlane(wb, k + 2));
            float w3 = __int_as_float(__builtin_amdgcn_readlane(wb, k + 3));
            EDGE4(y0, w0) EDGE4(y1, w1) EDGE4(y2, w2) EDGE4(y3, w3)
        }
        for (; k < nb; ++k) {                  // scalar tail (<=3)
            int s0 = __builtin_amdgcn_readlane(sx, k) & 0x1FFFF;
            float4 y0 = yv[s0];
            float w0 = __int_as_float(__builtin_amdgcn_readlane(wb, k));
            EDGE4(y0, w0)
        }
    }

    // aggr -> bf16 hi/lo (ONLY output; h1 recomputed in node2)
    {
        ushort hx = f2bf(acc.x);
        ushort lx = f2bf(acc.x - bf2f(hx));
        ushort hy = f2bf(acc.y);
        ushort ly = f2bf(acc.y - bf2f(hy));
        ushort2 hv2; hv2.x = hx; hv2.y = hy;
        ushort2 lv2; lv2.x = lx; lv2.y = ly;
        *reinterpret_cast<ushort2*>(a_hi + (size_t)wv * HIDDEN + c0) = hv2;
        *reinterpret_cast<ushort2*>(a_lo + (size_t)wv * HIDDEN + c0) = lv2;
    }
}

// ================= one-shot W2 split + transpose ============================
__global__ __launch_bounds__(256)
void k_splitw(const float* __restrict__ Wrel, const float* __restrict__ Wroot,
              ushort* __restrict__ wThi, ushort* __restrict__ wTlo) {
    int idx = blockIdx.x * 256 + threadIdx.x;   // 0..32767
    int k = idx >> 7;          // 0..255
    int n = idx & 127;
    float v = (k < 128) ? Wrel[(size_t)k * HIDDEN + n]
                        : Wroot[(size_t)(k - 128) * HIDDEN + n];
    ushort hb = f2bf(v);
    ushort lb = f2bf(v - bf2f(hb));
    wThi[(size_t)n * 256 + k] = hb;
    wTlo[(size_t)n * 256 + k] = lb;
}

// ============ layer-2 node update on the MATRIX pipe + layer-3 fusion =======
// (R21 structure: W1 in LDS, lean 2x4-col h1 recompute for t>=4.)
#define BM2 64
#define W3_STRIDE 7
#define XS_LD 40   // ushorts per LDS row: 32 k + 8 pad (80B, 16B-aligned)

__global__ __launch_bounds__(256)
void k_node2(const ushort* __restrict__ a_hi, const ushort* __restrict__ a_lo,
             const float4* __restrict__ yv,
             const float* __restrict__ W1rel, const float* __restrict__ b1,
             const float* __restrict__ W1root,
             const ushort* __restrict__ wThi, const ushort* __restrict__ wTlo,
             const float* __restrict__ b,
             const float* __restrict__ W3rel, const float* __restrict__ b3,
             const float* __restrict__ W3root,
             float* __restrict__ z, float* __restrict__ out, int N) {
    __shared__ __align__(16) ushort Xhi[BM2 * XS_LD];
    __shared__ __align__(16) ushort Xlo[BM2 * XS_LD];
    __shared__ __align__(16) ushort Whi[HIDDEN * XS_LD];
    __shared__ __align__(16) ushort Wlo[HIDDEN * XS_LD];
    __shared__ float W3s[HIDDEN * W3_STRIDE];
    __shared__ __align__(16) float W1s[5 * HIDDEN];  // [0]=b1 [1,2]=W1rel [3,4]=W1root

    const int tid  = threadIdx.x;
    const int lane = tid & 63;
    const int wid  = tid >> 6;
    const int ci   = lane & 15;
    const int kb   = lane >> 4;          // k-block 0..3
    const int nb   = blockIdx.x * BM2;

    if (tid < HIDDEN) {
#pragma unroll
        for (int c = 0; c < 3; ++c) {
            W3s[tid * W3_STRIDE + c]     = W3rel [tid * 3 + c];
            W3s[tid * W3_STRIDE + 3 + c] = W3root[tid * 3 + c];
        }
        W1s[0 * HIDDEN + tid] = b1[tid];
        W1s[1 * HIDDEN + tid] = W1rel[tid];
        W1s[2 * HIDDEN + tid] = W1rel[HIDDEN + tid];
        W1s[3 * HIDDEN + tid] = W1root[tid];
        W1s[4 * HIDDEN + tid] = W1root[HIDDEN + tid];
    }

    f32x4 acc[8];
#pragma unroll
    for (int tile = 0; tile < 8; ++tile) {
        float bb = b[tile * 16 + ci];
        f32x4 v; v[0] = bb; v[1] = bb; v[2] = bb; v[3] = bb;
        acc[tile] = v;
    }

    // staging index precompute
    const int sr  = tid >> 2;            // X row 0..63
    const int skq = (tid & 3) * 8;       // X k offset {0,8,16,24}

    // K = 256: 8 phases of 32. t<4: aggr from global; t>=4: h1 RECOMPUTED.
    for (int t = 0; t < 8; ++t) {
        const int kc = (t & 3) * 32;

        __syncthreads();                 // previous compute done before overwrite
        if (t < 4) {
            // stage aggr tile (pre-split bf16): 1 b128 per array per thread
            int gr = nb + sr; if (gr >= N) gr = N - 1;
            size_t gofs = (size_t)gr * HIDDEN + kc + skq;
            *reinterpret_cast<short8*>(&Xhi[sr * XS_LD + skq]) =
                *reinterpret_cast<const short8*>(a_hi + gofs);
            *reinterpret_cast<short8*>(&Xlo[sr * XS_LD + skq]) =
                *reinterpret_cast<const short8*>(a_lo + gofs);
        } else {
            // recompute h1 cols [kc+skq, +8) for row sr from yv + LDS W1
            int gr = nb + sr; if (gr >= N) gr = N - 1;
            float4 y = yv[gr];
#pragma unroll
            for (int g = 0; g < 2; ++g) {
                int cc = kc + skq + g * 4;
                float4 bb = *reinterpret_cast<const float4*>(&W1s[0 * HIDDEN + cc]);
                float4 r0 = *reinterpret_cast<const float4*>(&W1s[1 * HIDDEN + cc]);
                float4 r1 = *reinterpret_cast<const float4*>(&W1s[2 * HIDDEN + cc]);
                float4 o0 = *reinterpret_cast<const float4*>(&W1s[3 * HIDDEN + cc]);
                float4 o1 = *reinterpret_cast<const float4*>(&W1s[4 * HIDDEN + cc]);
                float v0 = fmaf(y.x, r0.x, bb.x); v0 = fmaf(y.y, r1.x, v0);
                v0 = fmaf(y.z, o0.x, v0); v0 = fmaf(y.w, o1.x, v0); v0 = fmaxf(v0, 0.f);
                float v1 = fmaf(y.x, r0.y, bb.y); v1 = fmaf(y.y, r1.y, v1);
                v1 = fmaf(y.z, o0.y, v1); v1 = fmaf(y.w, o1.y, v1); v1 = fmaxf(v1, 0.f);
                float v2 = fmaf(y.x, r0.z, bb.z); v2 = fmaf(y.y, r1.z, v2);
                v2 = fmaf(y.z, o0.z, v2); v2 = fmaf(y.w, o1.z, v2); v2 = fmaxf(v2, 0.f);
                float v3 = fmaf(y.x, r0.w, bb.w); v3 = fmaf(y.y, r1.w, v3);
                v3 = fmaf(y.z, o0.w, v3); v3 = fmaf(y.w, o1.w, v3); v3 = fmaxf(v3, 0.f);
                ushort4 hu, lu;
                hu.x = f2bf(v0); lu.x = f2bf(v0 - bf2f(hu.x));
                hu.y = f2bf(v1); lu.y = f2bf(v1 - bf2f(hu.y));
                hu.z = f2bf(v2); lu.z = f2bf(v2 - bf2f(hu.z));
                hu.w = f2bf(v3); lu.w = f2bf(v3 - bf2f(hu.w));
                *reinterpret_cast<ushort4*>(&Xhi[sr * XS_LD + skq + g * 4]) = hu;
                *reinterpret_cast<ushort4*>(&Xlo[sr * XS_LD + skq + g * 4]) = lu;
            }
        }
        // stage W tile: pure b128 copy from pre-split pre-transposed wT
#pragma unroll
        for (int q = 0; q < 2; ++q) {
            int idx = q * 256 + tid;     // 0..511
            int n  = idx >> 2;           // 0..127
            int kq = (idx & 3) * 8;      // 0,8,16,24
            size_t g = (size_t)n * 256 + t * 32 + kq;
            *reinterpret_cast<short8*>(&Whi[n * XS_LD + kq]) =
                *reinterpret_cast<const short8*>(wThi + g);
            *reinterpret_cast<short8*>(&Wlo[n * XS_LD + kq]) =
                *reinterpret_cast<const short8*>(wTlo + g);
        }
        __syncthreads();

        // A frags for this wave's 16-row tile (shared across all col tiles)
        int rl = wid * 16 + ci;
        short8 afh = *reinterpret_cast<const short8*>(&Xhi[rl * XS_LD + kb * 8]);
        short8 afl = *reinterpret_cast<const short8*>(&Xlo[rl * XS_LD + kb * 8]);
#pragma unroll
        for (int tile = 0; tile < 8; ++tile) {
            int nl = tile * 16 + ci;
            short8 bfh = *reinterpret_cast<const short8*>(&Whi[nl * XS_LD + kb * 8]);
            short8 bfl = *reinterpret_cast<const short8*>(&Wlo[nl * XS_LD + kb * 8]);
            acc[tile] = __builtin_amdgcn_mfma_f32_16x16x32_bf16(afh, bfh, acc[tile], 0, 0, 0);
            acc[tile] = __builtin_amdgcn_mfma_f32_16x16x32_bf16(afh, bfl, acc[tile], 0, 0, 0);
            acc[tile] = __builtin_amdgcn_mfma_f32_16x16x32_bf16(afl, bfh, acc[tile], 0, 0, 0);
        }
    }

    // epilogue: relu -> per-thread rank-8 partials vs LDS W3 -> width-16 shfl
    const float b30 = b3[0], b31 = b3[1], b32 = b3[2];
#pragma unroll
    for (int m = 0; m < 4; ++m) {
        int node = nb + wid * 16 + kb * 4 + m;
        float zr0 = 0.f, zr1 = 0.f, zr2 = 0.f;
        float zo0 = 0.f, zo1 = 0.f, zo2 = 0.f;
#pragma unroll
        for (int tile = 0; tile < 8; ++tile) {
            float hv = fmaxf(acc[tile][m], 0.f);
            const float* w3 = &W3s[(tile * 16 + ci) * W3_STRIDE];
            zr0 = fmaf(hv, w3[0], zr0); zr1 = fmaf(hv, w3[1], zr1); zr2 = fmaf(hv, w3[2], zr2);
            zo0 = fmaf(hv, w3[3], zo0); zo1 = fmaf(hv, w3[4], zo1); zo2 = fmaf(hv, w3[5], zo2);
        }
#pragma unroll
        for (int d = 8; d >= 1; d >>= 1) {
            zr0 += __shfl_down(zr0, d, 16);
            zr1 += __shfl_down(zr1, d, 16);
            zr2 += __shfl_down(zr2, d, 16);
            zo0 += __shfl_down(zo0, d, 16);
            zo1 += __shfl_down(zo1, d, 16);
            zo2 += __shfl_down(zo2, d, 16);
        }
        if (ci == 0 && node < N) {
            z[(size_t)node * 3 + 0] = zr0;
            z[(size_t)node * 3 + 1] = zr1;
            z[(size_t)node * 3 + 2] = zr2;
            out[(size_t)node * 3 + 0] = zo0 + b30;
            out[(size_t)node * 3 + 1] = zo1 + b31;
            out[(size_t)node * 3 + 2] = zo2 + b32;
        }
    }
}

// ================= layer 3 gather: block-per-bucket, LDS fp32 atomics =======
// R23: replaces the serial thread-per-node loop (~16 dependent cpack->z
// chains/thread, the structure that made old k_gather2 cost ~20us).
// Streaming coalesced cpack read + pipelined L2 z loads + LDS atomics.
__global__ __launch_bounds__(512)
void k_gather3(const int* __restrict__ offs, const int2* __restrict__ cpack,
               const float* __restrict__ z, float* __restrict__ out,
               int N, int E, int NB) {
    __shared__ float agg3[512 * 3];
    int b = blockIdx.x;
    int t = threadIdx.x;
    agg3[t] = 0.f; agg3[t + 512] = 0.f; agg3[t + 1024] = 0.f;
    __syncthreads();
    int nb0 = b << CBITS;
    int ebeg = offs[nb0];
    int eend = (b + 1 < NB) ? offs[(b + 1) << CBITS] : E;
    for (int e = ebeg + t; e < eend; e += 512) {
        int2 p = cpack[e];
        int dl = (p.x >> 17) & 511;
        int srcn = p.x & 0x1FFFF;
        float w = __int_as_float(p.y);
        const float* zp = z + (size_t)srcn * 3;
        float2 z01 = *reinterpret_cast<const float2*>(zp);
        float z2 = zp[2];
        atomicAdd(&agg3[dl * 3 + 0], w * z01.x);
        atomicAdd(&agg3[dl * 3 + 1], w * z01.y);
        atomicAdd(&agg3[dl * 3 + 2], w * z2);
    }
    __syncthreads();
    int node = nb0 + t;
    if (node < N) {
        out[(size_t)node * 3 + 0] += agg3[t * 3 + 0];
        out[(size_t)node * 3 + 1] += agg3[t * 3 + 1];
        out[(size_t)node * 3 + 2] += agg3[t * 3 + 2];
    }
}

extern "C" void kernel_launch(void* const* d_in, const int* in_sizes, int n_in,
                              void* d_out, int out_size, void* d_ws, size_t ws_size,
                              hipStream_t stream) {
    const float* x      = (const float*)d_in[0];
    const int*   ei     = (const int*)  d_in[1];
    const float* ew     = (const float*)d_in[2];
    const float* W1rel  = (const float*)d_in[4];
    const float* b1     = (const float*)d_in[5];
    const float* W1root = (const float*)d_in[6];
    const float* W2rel  = (const float*)d_in[7];
    const float* b2     = (const float*)d_in[8];
    const float* W2root = (const float*)d_in[9];
    const float* W3rel  = (const float*)d_in[10];
    const float* b3     = (const float*)d_in[11];
    const float* W3root = (const float*)d_in[12];
    float* out = (float*)d_out;

    const int N = in_sizes[0] / 2;
    const int E = in_sizes[2];
    const int* src = ei;
    const int* dst = ei + E;

    // -------- workspace layout (same reservation as R22) --------
    ushort* hregion = (ushort*)d_ws;       // reserved
    ushort* a_hi = hregion + 2 * (size_t)N * HIDDEN;
    ushort* a_lo = a_hi + (size_t)N * HIDDEN;
    int*   offs = (int*)(a_lo + (size_t)N * HIDDEN);
    size_t cpo  = (size_t)(offs + N - (int*)d_ws);
    cpo = (cpo + 1) & ~(size_t)1;          // 8B alignment
    int2*   cpack = (int2*)((int*)d_ws + cpo);
    size_t yvo  = (size_t)((char*)(cpack + E) - (char*)d_ws);
    yvo = (yvo + 15) & ~(size_t)15;        // 16B alignment
    float4* yv  = (float4*)((char*)d_ws + yvo);

    // h-region aliases:
    int2* staged = (int2*)d_ws;            // CSR build only
    float* z = (float*)d_ws;               // written by node2 (staged dead)
    size_t wto = ((size_t)N * 3 * sizeof(float) + 63) & ~(size_t)63;
    ushort* wThi = (ushort*)((char*)d_ws + wto);          // 64KB
    ushort* wTlo = wThi + 128 * 256;                       // 64KB
    // a-region aliases (CSR build only; dead before gatherfused writes a):
    int*  bh     = (int*)a_hi;             // 256KB
    int*  choff  = bh + 256 * 256;         // 256KB
    int*  bbase  = choff + 256 * 256;      // 257 ints

    const int CS = (E + NCHUNK - 1) / NCHUNK;
    const int NB = (N + 511) >> CBITS;     // coarse buckets (needs N < 2^17)

    // -------- CSR build: counting sort + fused layer-1 aggregation ---------
    k_bhist  <<<NCHUNK, 256, 0, stream>>>(dst, bh, E, CS);
    k_cscan  <<<1, 256, 0, stream>>>(bh, choff, bbase);
    k_scatter<<<NCHUNK, 256, 0, stream>>>(src, dst, ew, choff, bbase, staged, E, CS);
    k_fine   <<<NB, 512, 0, stream>>>(staged, bbase, x, offs, cpack, yv, N);

    // -------- fused layer-2 aggregation (bf16 out; h1 never materialized) ---
    {
        long long threads = (long long)N * 64;
        k_gatherfused<<<(int)((threads + 255) / 256), 256, 0, stream>>>(
            offs, cpack, yv, W1rel, b1, W1root, a_hi, a_lo, N, E);
    }

    // -------- one-shot W2 split+transpose (staged dead; writes h region) ----
    k_splitw<<<128, 256, 0, stream>>>(W2rel, W2root, wThi, wTlo);

    // -------- MFMA layer-2 node update + layer-3 projection --------
    k_node2<<<(N + BM2 - 1) / BM2, 256, 0, stream>>>(
        a_hi, a_lo, yv, W1rel, b1, W1root, wThi, wTlo,
        b2, W3rel, b3, W3root, z, out, N);

    // -------- layer 3 gather (bucket blocks + LDS atomics) --------
    k_gather3<<<NB, 512, 0, stream>>>(offs, cpack, z, out, N, E, NB);
}

// Round 24
// 190.682 us; speedup vs baseline: 1.1165x; 1.1165x over previous
//
#include <hip/hip_runtime.h>

#define HIDDEN 128
#define NCHUNK 256
#define CBITS  9            // 512 nodes per coarse bucket (needs N < 2^17)

typedef float v2f __attribute__((ext_vector_type(2)));
typedef short short8 __attribute__((ext_vector_type(8)));
typedef float f32x4 __attribute__((ext_vector_type(4)));
__device__ __forceinline__ v2f v2s(float a) { v2f r; r.x = a; r.y = a; return r; }

// bf16 split helpers (RNE)
__device__ __forceinline__ ushort f2bf(float f) {
    uint u = __float_as_uint(f);
    u += 0x7FFFu + ((u >> 16) & 1u);
    return (ushort)(u >> 16);
}
__device__ __forceinline__ float bf2f(ushort h) {
    return __uint_as_float(((uint)h) << 16);
}

// ============== CSR build via two-level counting sort (NO global atomics) ===
__global__ __launch_bounds__(256)
void k_bhist(const int* __restrict__ dst, int* __restrict__ bh, int E, int CS) {
    __shared__ int h[256];
    int c = blockIdx.x;
    h[threadIdx.x] = 0;
    __syncthreads();
    int beg = c * CS, end = min(E, beg + CS);
    for (int e = beg + threadIdx.x; e < end; e += 256)
        atomicAdd(&h[dst[e] >> CBITS], 1);
    __syncthreads();
    bh[c * 256 + threadIdx.x] = h[threadIdx.x];
}

__global__ __launch_bounds__(256)
void k_cscan(const int* __restrict__ bh, int* __restrict__ choff,
             int* __restrict__ bbase) {
    __shared__ int sm[256];
    int b = threadIdx.x;
    int acc = 0;
    for (int c = 0; c < NCHUNK; c += 8) {
        int v[8];
#pragma unroll
        for (int i = 0; i < 8; ++i) v[i] = bh[(c + i) * 256 + b];
#pragma unroll
        for (int i = 0; i < 8; ++i) { choff[(c + i) * 256 + b] = acc; acc += v[i]; }
    }
    int tot = acc;
    sm[b] = tot;
    __syncthreads();
    int run = tot;
    for (int d = 1; d < 256; d <<= 1) {
        int t = (b >= d) ? sm[b - d] : 0;
        __syncthreads();
        run += t;
        sm[b] = run;
        __syncthreads();
    }
    bbase[b] = run - tot;              // exclusive
    if (b == 255) bbase[256] = run;    // == E
}

__global__ __launch_bounds__(256)
void k_scatter(const int* __restrict__ src, const int* __restrict__ dst,
               const float* __restrict__ ew, const int* __restrict__ choff,
               const int* __restrict__ bbase, int2* __restrict__ staged,
               int E, int CS) {
    __shared__ int cur[256];
    int c = blockIdx.x;
    cur[threadIdx.x] = bbase[threadIdx.x] + choff[c * 256 + threadIdx.x];
    __syncthreads();
    int beg = c * CS, end = min(E, beg + CS);
    for (int e = beg + threadIdx.x; e < end; e += 256) {
        int d = dst[e];
        int slot = atomicAdd(&cur[d >> CBITS], 1);
        int2 p;
        p.x = src[e] | ((d & 511) << 17);
        p.y = __float_as_int(ew[e]);
        staged[slot] = p;
    }
}

// Pass D: per-bucket fine CSR + FUSED layer-1 aggregation (R22 exact).
__global__ __launch_bounds__(512)
void k_fine(const int2* __restrict__ staged, const int* __restrict__ bbase,
            const float* __restrict__ x,
            int* __restrict__ offs, int2* __restrict__ cpack,
            float4* __restrict__ yv, int N) {
    __shared__ int fc[512];
    __shared__ int fo[512];
    __shared__ int sm[512];
    __shared__ float agg[1024];
    int b = blockIdx.x;
    int t = threadIdx.x;
    int ebeg = bbase[b], eend = bbase[b + 1];
    fc[t] = 0;
    agg[t] = 0.f;
    agg[t + 512] = 0.f;
    __syncthreads();
    for (int e = ebeg + t; e < eend; e += 512)
        atomicAdd(&fc[(staged[e].x >> 17) & 511], 1);
    __syncthreads();
    // exclusive scan of 512 (1 elem/thread)
    int v = fc[t];
    sm[t] = v;
    __syncthreads();
    int run = v;
    for (int d = 1; d < 512; d <<= 1) {
        int u = (t >= d) ? sm[t - d] : 0;
        __syncthreads();
        run += u;
        sm[t] = run;
        __syncthreads();
    }
    fo[t] = run - v;                   // exclusive
    __syncthreads();
    int nb0 = b << CBITS;
    int node = nb0 + t;
    if (node < N) offs[node] = ebeg + fo[t];
    __syncthreads();                   // offs reads of fo done before cursor use
    for (int e = ebeg + t; e < eend; e += 512) {
        int2 p = staged[e];
        int dl = (p.x >> 17) & 511;
        int srcn = p.x & 0x1FFFF;
        float w = __int_as_float(p.y);
        int ls = atomicAdd(&fo[dl], 1);
        int2 q2;
        q2.x = srcn;
        q2.y = p.y;
        cpack[ebeg + ls] = q2;
        float2 xv = *reinterpret_cast<const float2*>(x + (size_t)srcn * 2);
        atomicAdd(&agg[dl * 2 + 0], w * xv.x);
        atomicAdd(&agg[dl * 2 + 1], w * xv.y);
    }
    __syncthreads();
    if (node < N) {
        float2 xi = *reinterpret_cast<const float2*>(x + (size_t)node * 2);
        yv[node] = make_float4(agg[2 * t], agg[2 * t + 1], xi.x, xi.y);
    }
}

__device__ __forceinline__ int end_of(const int* offs, int i, int N, int E) {
    return (i + 1 < N) ? offs[i + 1] : E;
}

// ================= fused layer-2 aggregation (+ implicit layer-1) ===========
// (R20 structure: h1 never materialized; only a_hi/a_lo written.)
#define EDGE4(sK, wK)                                              \
    {                                                              \
        v2f t = B + v2s((sK).x) * WR0 + v2s((sK).y) * WR1          \
                  + v2s((sK).z) * WO0 + v2s((sK).w) * WO1;         \
        t = __builtin_elementwise_max(t, Z);                       \
        acc = acc + v2s(wK) * t;                                   \
    }

__global__ __launch_bounds__(256)
void k_gatherfused(const int* __restrict__ offs, const int2* __restrict__ cpack,
                   const float4* __restrict__ yv,
                   const float* __restrict__ W1rel, const float* __restrict__ b1,
                   const float* __restrict__ W1root,
                   ushort* __restrict__ a_hi, ushort* __restrict__ a_lo,
                   int N, int E) {
    int wv   = (blockIdx.x * 256 + threadIdx.x) >> 6;
    int lane = threadIdx.x & 63;
    if (wv >= N) return;
    wv = __builtin_amdgcn_readfirstlane(wv);   // force scalar: loop control uniform

    const int c0 = lane * 2;
    const v2f WR0 = *reinterpret_cast<const v2f*>(W1rel  + c0);
    const v2f WR1 = *reinterpret_cast<const v2f*>(W1rel  + HIDDEN + c0);
    const v2f WO0 = *reinterpret_cast<const v2f*>(W1root + c0);
    const v2f WO1 = *reinterpret_cast<const v2f*>(W1root + HIDDEN + c0);
    const v2f B   = *reinterpret_cast<const v2f*>(b1 + c0);
    const v2f Z   = {0.f, 0.f};

    int start = offs[wv];
    int end   = (wv + 1 < N) ? offs[wv + 1] : E;
    v2f acc = {0.f, 0.f};

    for (int base = start; base < end; base += 64) {
        int nb = min(64, end - base);
        int sx = 0, wb = 0;
        if (lane < nb) {                       // ONE coalesced 8B/lane load
            int2 p = cpack[base + lane];
            sx = p.x; wb = p.y;
        }
        int k = 0;
        for (; k + 8 <= nb; k += 8) {
            int s0 = __builtin_amdgcn_readlane(sx, k + 0);
            int s1 = __builtin_amdgcn_readlane(sx, k + 1);
            int s2 = __builtin_amdgcn_readlane(sx, k + 2);
            int s3 = __builtin_amdgcn_readlane(sx, k + 3);
            int s4 = __builtin_amdgcn_readlane(sx, k + 4);
            int s5 = __builtin_amdgcn_readlane(sx, k + 5);
            int s6 = __builtin_amdgcn_readlane(sx, k + 6);
            int s7 = __builtin_amdgcn_readlane(sx, k + 7);
            float4 y0 = yv[s0]; float4 y1 = yv[s1];
            float4 y2 = yv[s2]; float4 y3 = yv[s3];
            float4 y4 = yv[s4]; float4 y5 = yv[s5];
            float4 y6 = yv[s6]; float4 y7 = yv[s7];
            float w0 = __int_as_float(__builtin_amdgcn_readlane(wb, k + 0));
            float w1 = __int_as_float(__builtin_amdgcn_readlane(wb, k + 1));
            float w2 = __int_as_float(__builtin_amdgcn_readlane(wb, k + 2));
            float w3 = __int_as_float(__builtin_amdgcn_readlane(wb, k + 3));
            float w4 = __int_as_float(__builtin_amdgcn_readlane(wb, k + 4));
            float w5 = __int_as_float(__builtin_amdgcn_readlane(wb, k + 5));
            float w6 = __int_as_float(__builtin_amdgcn_readlane(wb, k + 6));
            float w7 = __int_as_float(__builtin_amdgcn_readlane(wb, k + 7));
            EDGE4(y0, w0) EDGE4(y1, w1) EDGE4(y2, w2) EDGE4(y3, w3)
            EDGE4(y4, w4) EDGE4(y5, w5) EDGE4(y6, w6) EDGE4(y7, w7)
        }
        for (; k + 4 <= nb; k += 4) {
            int s0 = __builtin_amdgcn_readlane(sx, k + 0);
            int s1 = __builtin_amdgcn_readlane(sx, k + 1);
            int s2 = __builtin_amdgcn_readlane(sx, k + 2);
            int s3 = __builtin_amdgcn_readlane(sx, k + 3);
            float4 y0 = yv[s0]; float4 y1 = yv[s1];
            float4 y2 = yv[s2]; float4 y3 = yv[s3];
            float w0 = __int_as_float(__builtin_amdgcn_readlane(wb, k + 0));
            float w1 = __int_as_float(__builtin_amdgcn_readlane(wb, k + 1));
            float w2 = __int_as_float(__builtin_amdgcn_readlane(wb, k + 2));
            float w3 = __int_as_float(__builtin_amdgcn_readlane(wb, k + 3));
            EDGE4(y0, w0) EDGE4(y1, w1) EDGE4(y2, w2) EDGE4(y3, w3)
        }
        for (; k < nb; ++k) {                  // scalar tail (<=3)
            int s0 = __builtin_amdgcn_readlane(sx, k);
            float4 y0 = yv[s0];
            float w0 = __int_as_float(__builtin_amdgcn_readlane(wb, k));
            EDGE4(y0, w0)
        }
    }

    // aggr -> bf16 hi/lo (ONLY output; h1 recomputed in node2)
    {
        ushort hx = f2bf(acc.x);
        ushort lx = f2bf(acc.x - bf2f(hx));
        ushort hy = f2bf(acc.y);
        ushort ly = f2bf(acc.y - bf2f(hy));
        ushort2 hv2; hv2.x = hx; hv2.y = hy;
        ushort2 lv2; lv2.x = lx; lv2.y = ly;
        *reinterpret_cast<ushort2*>(a_hi + (size_t)wv * HIDDEN + c0) = hv2;
        *reinterpret_cast<ushort2*>(a_lo + (size_t)wv * HIDDEN + c0) = lv2;
    }
}

// ================= one-shot W2 split + transpose ============================
__global__ __launch_bounds__(256)
void k_splitw(const float* __restrict__ Wrel, const float* __restrict__ Wroot,
              ushort* __restrict__ wThi, ushort* __restrict__ wTlo) {
    int idx = blockIdx.x * 256 + threadIdx.x;   // 0..32767
    int k = idx >> 7;          // 0..255
    int n = idx & 127;
    float v = (k < 128) ? Wrel[(size_t)k * HIDDEN + n]
                        : Wroot[(size_t)(k - 128) * HIDDEN + n];
    ushort hb = f2bf(v);
    ushort lb = f2bf(v - bf2f(hb));
    wThi[(size_t)n * 256 + k] = hb;
    wTlo[(size_t)n * 256 + k] = lb;
}

// ============ layer-2 node update on the MATRIX pipe + layer-3 fusion =======
// (R21 structure: W1 in LDS, lean 2x4-col h1 recompute for t>=4.)
#define BM2 64
#define W3_STRIDE 7
#define XS_LD 40   // ushorts per LDS row: 32 k + 8 pad (80B, 16B-aligned)

__global__ __launch_bounds__(256)
void k_node2(const ushort* __restrict__ a_hi, const ushort* __restrict__ a_lo,
             const float4* __restrict__ yv,
             const float* __restrict__ W1rel, const float* __restrict__ b1,
             const float* __restrict__ W1root,
             const ushort* __restrict__ wThi, const ushort* __restrict__ wTlo,
             const float* __restrict__ b,
             const float* __restrict__ W3rel, const float* __restrict__ b3,
             const float* __restrict__ W3root,
             float* __restrict__ z, float* __restrict__ out, int N) {
    __shared__ __align__(16) ushort Xhi[BM2 * XS_LD];
    __shared__ __align__(16) ushort Xlo[BM2 * XS_LD];
    __shared__ __align__(16) ushort Whi[HIDDEN * XS_LD];
    __shared__ __align__(16) ushort Wlo[HIDDEN * XS_LD];
    __shared__ float W3s[HIDDEN * W3_STRIDE];
    __shared__ __align__(16) float W1s[5 * HIDDEN];  // [0]=b1 [1,2]=W1rel [3,4]=W1root

    const int tid  = threadIdx.x;
    const int lane = tid & 63;
    const int wid  = tid >> 6;
    const int ci   = lane & 15;
    const int kb   = lane >> 4;          // k-block 0..3
    const int nb   = blockIdx.x * BM2;

    if (tid < HIDDEN) {
#pragma unroll
        for (int c = 0; c < 3; ++c) {
            W3s[tid * W3_STRIDE + c]     = W3rel [tid * 3 + c];
            W3s[tid * W3_STRIDE + 3 + c] = W3root[tid * 3 + c];
        }
        W1s[0 * HIDDEN + tid] = b1[tid];
        W1s[1 * HIDDEN + tid] = W1rel[tid];
        W1s[2 * HIDDEN + tid] = W1rel[HIDDEN + tid];
        W1s[3 * HIDDEN + tid] = W1root[tid];
        W1s[4 * HIDDEN + tid] = W1root[HIDDEN + tid];
    }

    f32x4 acc[8];
#pragma unroll
    for (int tile = 0; tile < 8; ++tile) {
        float bb = b[tile * 16 + ci];
        f32x4 v; v[0] = bb; v[1] = bb; v[2] = bb; v[3] = bb;
        acc[tile] = v;
    }

    // staging index precompute
    const int sr  = tid >> 2;            // X row 0..63
    const int skq = (tid & 3) * 8;       // X k offset {0,8,16,24}

    // K = 256: 8 phases of 32. t<4: aggr from global; t>=4: h1 RECOMPUTED.
    for (int t = 0; t < 8; ++t) {
        const int kc = (t & 3) * 32;

        __syncthreads();                 // previous compute done before overwrite
        if (t < 4) {
            // stage aggr tile (pre-split bf16): 1 b128 per array per thread
            int gr = nb + sr; if (gr >= N) gr = N - 1;
            size_t gofs = (size_t)gr * HIDDEN + kc + skq;
            *reinterpret_cast<short8*>(&Xhi[sr * XS_LD + skq]) =
                *reinterpret_cast<const short8*>(a_hi + gofs);
            *reinterpret_cast<short8*>(&Xlo[sr * XS_LD + skq]) =
                *reinterpret_cast<const short8*>(a_lo + gofs);
        } else {
            // recompute h1 cols [kc+skq, +8) for row sr from yv + LDS W1
            int gr = nb + sr; if (gr >= N) gr = N - 1;
            float4 y = yv[gr];
#pragma unroll
            for (int g = 0; g < 2; ++g) {
                int cc = kc + skq + g * 4;
                float4 bb = *reinterpret_cast<const float4*>(&W1s[0 * HIDDEN + cc]);
                float4 r0 = *reinterpret_cast<const float4*>(&W1s[1 * HIDDEN + cc]);
                float4 r1 = *reinterpret_cast<const float4*>(&W1s[2 * HIDDEN + cc]);
                float4 o0 = *reinterpret_cast<const float4*>(&W1s[3 * HIDDEN + cc]);
                float4 o1 = *reinterpret_cast<const float4*>(&W1s[4 * HIDDEN + cc]);
                float v0 = fmaf(y.x, r0.x, bb.x); v0 = fmaf(y.y, r1.x, v0);
                v0 = fmaf(y.z, o0.x, v0); v0 = fmaf(y.w, o1.x, v0); v0 = fmaxf(v0, 0.f);
                float v1 = fmaf(y.x, r0.y, bb.y); v1 = fmaf(y.y, r1.y, v1);
                v1 = fmaf(y.z, o0.y, v1); v1 = fmaf(y.w, o1.y, v1); v1 = fmaxf(v1, 0.f);
                float v2 = fmaf(y.x, r0.z, bb.z); v2 = fmaf(y.y, r1.z, v2);
                v2 = fmaf(y.z, o0.z, v2); v2 = fmaf(y.w, o1.z, v2); v2 = fmaxf(v2, 0.f);
                float v3 = fmaf(y.x, r0.w, bb.w); v3 = fmaf(y.y, r1.w, v3);
                v3 = fmaf(y.z, o0.w, v3); v3 = fmaf(y.w, o1.w, v3); v3 = fmaxf(v3, 0.f);
                ushort4 hu, lu;
                hu.x = f2bf(v0); lu.x = f2bf(v0 - bf2f(hu.x));
                hu.y = f2bf(v1); lu.y = f2bf(v1 - bf2f(hu.y));
                hu.z = f2bf(v2); lu.z = f2bf(v2 - bf2f(hu.z));
                hu.w = f2bf(v3); lu.w = f2bf(v3 - bf2f(hu.w));
                *reinterpret_cast<ushort4*>(&Xhi[sr * XS_LD + skq + g * 4]) = hu;
                *reinterpret_cast<ushort4*>(&Xlo[sr * XS_LD + skq + g * 4]) = lu;
            }
        }
        // stage W tile: pure b128 copy from pre-split pre-transposed wT
#pragma unroll
        for (int q = 0; q < 2; ++q) {
            int idx = q * 256 + tid;     // 0..511
            int n  = idx >> 2;           // 0..127
            int kq = (idx & 3) * 8;      // 0,8,16,24
            size_t g = (size_t)n * 256 + t * 32 + kq;
            *reinterpret_cast<short8*>(&Whi[n * XS_LD + kq]) =
                *reinterpret_cast<const short8*>(wThi + g);
            *reinterpret_cast<short8*>(&Wlo[n * XS_LD + kq]) =
                *reinterpret_cast<const short8*>(wTlo + g);
        }
        __syncthreads();

        // A frags for this wave's 16-row tile (shared across all col tiles)
        int rl = wid * 16 + ci;
        short8 afh = *reinterpret_cast<const short8*>(&Xhi[rl * XS_LD + kb * 8]);
        short8 afl = *reinterpret_cast<const short8*>(&Xlo[rl * XS_LD + kb * 8]);
#pragma unroll
        for (int tile = 0; tile < 8; ++tile) {
            int nl = tile * 16 + ci;
            short8 bfh = *reinterpret_cast<const short8*>(&Whi[nl * XS_LD + kb * 8]);
            short8 bfl = *reinterpret_cast<const short8*>(&Wlo[nl * XS_LD + kb * 8]);
            acc[tile] = __builtin_amdgcn_mfma_f32_16x16x32_bf16(afh, bfh, acc[tile], 0, 0, 0);
            acc[tile] = __builtin_amdgcn_mfma_f32_16x16x32_bf16(afh, bfl, acc[tile], 0, 0, 0);
            acc[tile] = __builtin_amdgcn_mfma_f32_16x16x32_bf16(afl, bfh, acc[tile], 0, 0, 0);
        }
    }

    // epilogue: relu -> per-thread rank-8 partials vs LDS W3 -> width-16 shfl
    const float b30 = b3[0], b31 = b3[1], b32 = b3[2];
#pragma unroll
    for (int m = 0; m < 4; ++m) {
        int node = nb + wid * 16 + kb * 4 + m;
        float zr0 = 0.f, zr1 = 0.f, zr2 = 0.f;
        float zo0 = 0.f, zo1 = 0.f, zo2 = 0.f;
#pragma unroll
        for (int tile = 0; tile < 8; ++tile) {
            float hv = fmaxf(acc[tile][m], 0.f);
            const float* w3 = &W3s[(tile * 16 + ci) * W3_STRIDE];
            zr0 = fmaf(hv, w3[0], zr0); zr1 = fmaf(hv, w3[1], zr1); zr2 = fmaf(hv, w3[2], zr2);
            zo0 = fmaf(hv, w3[3], zo0); zo1 = fmaf(hv, w3[4], zo1); zo2 = fmaf(hv, w3[5], zo2);
        }
#pragma unroll
        for (int d = 8; d >= 1; d >>= 1) {
            zr0 += __shfl_down(zr0, d, 16);
            zr1 += __shfl_down(zr1, d, 16);
            zr2 += __shfl_down(zr2, d, 16);
            zo0 += __shfl_down(zo0, d, 16);
            zo1 += __shfl_down(zo1, d, 16);
            zo2 += __shfl_down(zo2, d, 16);
        }
        if (ci == 0 && node < N) {
            z[(size_t)node * 3 + 0] = zr0;
            z[(size_t)node * 3 + 1] = zr1;
            z[(size_t)node * 3 + 2] = zr2;
            out[(size_t)node * 3 + 0] = zo0 + b30;
            out[(size_t)node * 3 + 1] = zo1 + b31;
            out[(size_t)node * 3 + 2] = zo2 + b32;
        }
    }
}

// ================= layer 3 gather (R22 serial form) =====================
__global__ __launch_bounds__(256)
void k_gather3(const int* __restrict__ offs, const int2* __restrict__ cpack,
               const float* __restrict__ z, float* __restrict__ out,
               int N, int E) {
    int i = blockIdx.x * 256 + threadIdx.x;
    if (i >= N) return;
    int start = offs[i], end = end_of(offs, i, N, E);
    float a0 = 0.f, a1 = 0.f, a2 = 0.f;
    for (int j = start; j < end; ++j) {
        int2  p = cpack[j];
        int   s = p.x;
        float w = __int_as_float(p.y);
        const float* zp = z + (size_t)s * 3;
        a0 = fmaf(w, zp[0], a0);
        a1 = fmaf(w, zp[1], a1);
        a2 = fmaf(w, zp[2], a2);
    }
    out[(size_t)i * 3 + 0] += a0;
    out[(size_t)i * 3 + 1] += a1;
    out[(size_t)i * 3 + 2] += a2;
}

extern "C" void kernel_launch(void* const* d_in, const int* in_sizes, int n_in,
                              void* d_out, int out_size, void* d_ws, size_t ws_size,
                              hipStream_t stream) {
    const float* x      = (const float*)d_in[0];
    const int*   ei     = (const int*)  d_in[1];
    const float* ew     = (const float*)d_in[2];
    const float* W1rel  = (const float*)d_in[4];
    const float* b1     = (const float*)d_in[5];
    const float* W1root = (const float*)d_in[6];
    const float* W2rel  = (const float*)d_in[7];
    const float* b2     = (const float*)d_in[8];
    const float* W2root = (const float*)d_in[9];
    const float* W3rel  = (const float*)d_in[10];
    const float* b3     = (const float*)d_in[11];
    const float* W3root = (const float*)d_in[12];
    float* out = (float*)d_out;

    const int N = in_sizes[0] / 2;
    const int E = in_sizes[2];
    const int* src = ei;
    const int* dst = ei + E;

    // -------- workspace layout (same reservation as R22) --------
    ushort* hregion = (ushort*)d_ws;       // reserved
    ushort* a_hi = hregion + 2 * (size_t)N * HIDDEN;
    ushort* a_lo = a_hi + (size_t)N * HIDDEN;
    int*   offs = (int*)(a_lo + (size_t)N * HIDDEN);
    size_t cpo  = (size_t)(offs + N - (int*)d_ws);
    cpo = (cpo + 1) & ~(size_t)1;          // 8B alignment
    int2*   cpack = (int2*)((int*)d_ws + cpo);
    size_t yvo  = (size_t)((char*)(cpack + E) - (char*)d_ws);
    yvo = (yvo + 15) & ~(size_t)15;        // 16B alignment
    float4* yv  = (float4*)((char*)d_ws + yvo);

    // h-region aliases:
    int2* staged = (int2*)d_ws;            // CSR build only
    float* z = (float*)d_ws;               // written by node2 (staged dead)
    size_t wto = ((size_t)N * 3 * sizeof(float) + 63) & ~(size_t)63;
    ushort* wThi = (ushort*)((char*)d_ws + wto);          // 64KB
    ushort* wTlo = wThi + 128 * 256;                       // 64KB
    // a-region aliases (CSR build only; dead before gatherfused writes a):
    int*  bh     = (int*)a_hi;             // 256KB
    int*  choff  = bh + 256 * 256;         // 256KB
    int*  bbase  = choff + 256 * 256;      // 257 ints

    const int CS = (E + NCHUNK - 1) / NCHUNK;
    const int NB = (N + 511) >> CBITS;     // coarse buckets (needs N < 2^17)

    // -------- CSR build: counting sort + fused layer-1 aggregation ---------
    k_bhist  <<<NCHUNK, 256, 0, stream>>>(dst, bh, E, CS);
    k_cscan  <<<1, 256, 0, stream>>>(bh, choff, bbase);
    k_scatter<<<NCHUNK, 256, 0, stream>>>(src, dst, ew, choff, bbase, staged, E, CS);
    k_fine   <<<NB, 512, 0, stream>>>(staged, bbase, x, offs, cpack, yv, N);

    // -------- fused layer-2 aggregation (bf16 out; h1 never materialized) ---
    {
        long long threads = (long long)N * 64;
        k_gatherfused<<<(int)((threads + 255) / 256), 256, 0, stream>>>(
            offs, cpack, yv, W1rel, b1, W1root, a_hi, a_lo, N, E);
    }

    // -------- one-shot W2 split+transpose (staged dead; writes h region) ----
    k_splitw<<<128, 256, 0, stream>>>(W2rel, W2root, wThi, wTlo);

    // -------- MFMA layer-2 node update + layer-3 projection --------
    k_node2<<<(N + BM2 - 1) / BM2, 256, 0, stream>>>(
        a_hi, a_lo, yv, W1rel, b1, W1root, wThi, wTlo,
        b2, W3rel, b3, W3root, z, out, N);

    // -------- layer 3 gather --------
    k_gather3<<<(N + 255) / 256, 256, 0, stream>>>(offs, cpack, z, out, N, E);
}